// Round 1
// baseline (702.147 us; speedup 1.0000x reference)
//
#include <hip/hip_runtime.h>

#define N_NODES 50000
#define N_EDGES 800000
#define DIM 256

// ---------------- CSR build ----------------

__global__ void k_deg(const int* __restrict__ dst, int* __restrict__ deg) {
  int e = blockIdx.x * blockDim.x + threadIdx.x;
  if (e < N_EDGES) atomicAdd(&deg[dst[e]], 1);
}

__global__ void k_dinv(const int* __restrict__ deg, float* __restrict__ dinv) {
  int i = blockIdx.x * blockDim.x + threadIdx.x;
  if (i < N_NODES) dinv[i] = rsqrtf((float)(deg[i] + 1));  // +1 self-loop
}

__global__ __launch_bounds__(1024) void k_scan(const int* __restrict__ deg,
                                               int* __restrict__ row_start,
                                               int* __restrict__ cursor) {
  __shared__ int sums[1024];
  const int t = threadIdx.x;
  const int CH = (N_NODES + 1023) / 1024;  // 49
  int begin = t * CH;
  int end = begin + CH; if (end > N_NODES) end = N_NODES;
  int s = 0;
  for (int i = begin; i < end; ++i) s += deg[i];
  sums[t] = s;
  __syncthreads();
  for (int off = 1; off < 1024; off <<= 1) {
    int v = (t >= off) ? sums[t - off] : 0;
    __syncthreads();
    sums[t] += v;
    __syncthreads();
  }
  int run = sums[t] - s;  // exclusive prefix
  for (int i = begin; i < end; ++i) {
    row_start[i] = run;
    cursor[i] = run;
    run += deg[i];
  }
  if (t == 1023) row_start[N_NODES] = sums[1023];
}

__global__ void k_scatter(const int* __restrict__ src, const int* __restrict__ dst,
                          int* __restrict__ cursor, int* __restrict__ colidx) {
  int e = blockIdx.x * blockDim.x + threadIdx.x;
  if (e < N_EDGES) {
    int p = atomicAdd(&cursor[dst[e]], 1);
    colidx[p] = src[e];
  }
}

// ---------------- GEMM: XW = X @ W  (f32, 64x256 tile, Kc=32) ----------------
// B-tile stored with 16B-unit XOR swizzle: slot = u ^ ((u>>2)&7) so the 16
// col-chunk b128 reads per wave spread over all 8 bank windows (2-way = free).

__global__ __launch_bounds__(256) void k_gemm(const float* __restrict__ X,
                                              const float* __restrict__ W,
                                              float* __restrict__ XW) {
  __shared__ float As[32 * 64];    // [k][row] transposed, 8KB
  __shared__ float Bs[32 * 256];   // [k][swizzled col], 32KB
  const int tid = threadIdx.x;
  const int m0 = blockIdx.x * 64;
  const int rg = tid >> 4;   // 0..15 row group (4 rows each)
  const int cg = tid & 15;   // 0..15 col group (16 cols each)

  float acc[4][16];
#pragma unroll
  for (int r = 0; r < 4; ++r)
#pragma unroll
    for (int c = 0; c < 16; ++c) acc[r][c] = 0.f;

  for (int k0 = 0; k0 < DIM; k0 += 32) {
    // stage A (transpose to [k][row])
#pragma unroll
    for (int it = 0; it < 2; ++it) {
      int idx = tid + it * 256;
      int row_l = idx >> 3;
      int k4 = idx & 7;
      float4 v = make_float4(0.f, 0.f, 0.f, 0.f);
      int grow = m0 + row_l;
      if (grow < N_NODES)
        v = *reinterpret_cast<const float4*>(&X[grow * DIM + k0 + k4 * 4]);
      As[(k4 * 4 + 0) * 64 + row_l] = v.x;
      As[(k4 * 4 + 1) * 64 + row_l] = v.y;
      As[(k4 * 4 + 2) * 64 + row_l] = v.z;
      As[(k4 * 4 + 3) * 64 + row_l] = v.w;
    }
    // stage B (swizzled)
#pragma unroll
    for (int it = 0; it < 8; ++it) {
      int idx = tid + it * 256;
      int k_l = idx >> 6;
      int u = idx & 63;
      int slot = u ^ ((u >> 2) & 7);
      float4 v = *reinterpret_cast<const float4*>(&W[(k0 + k_l) * DIM + u * 4]);
      *reinterpret_cast<float4*>(&Bs[k_l * 256 + slot * 4]) = v;
    }
    __syncthreads();
#pragma unroll 4
    for (int k = 0; k < 32; ++k) {
      float4 a4 = *reinterpret_cast<const float4*>(&As[k * 64 + rg * 4]);
      float av[4] = {a4.x, a4.y, a4.z, a4.w};
#pragma unroll
      for (int rr = 0; rr < 4; ++rr) {
        int u = cg * 4 + rr;
        int slot = u ^ ((u >> 2) & 7);
        float4 b4 = *reinterpret_cast<const float4*>(&Bs[k * 256 + slot * 4]);
        float bv[4] = {b4.x, b4.y, b4.z, b4.w};
#pragma unroll
        for (int r = 0; r < 4; ++r)
#pragma unroll
          for (int j = 0; j < 4; ++j)
            acc[r][rr * 4 + j] += av[r] * bv[j];
      }
    }
    __syncthreads();
  }
#pragma unroll
  for (int r = 0; r < 4; ++r) {
    int grow = m0 + rg * 4 + r;
    if (grow >= N_NODES) continue;
#pragma unroll
    for (int rr = 0; rr < 4; ++rr) {
      float4 v = make_float4(acc[r][rr * 4 + 0], acc[r][rr * 4 + 1],
                             acc[r][rr * 4 + 2], acc[r][rr * 4 + 3]);
      *reinterpret_cast<float4*>(&XW[grow * DIM + cg * 16 + rr * 4]) = v;
    }
  }
}

// ---------------- aggregation: one wave per dst row ----------------

__global__ __launch_bounds__(256) void k_agg1(
    const float* __restrict__ xw, const int* __restrict__ row_start,
    const int* __restrict__ colidx, const float* __restrict__ dinv,
    const float* __restrict__ bias, const float* __restrict__ slope,
    float* __restrict__ z1) {
  const int wid = (blockIdx.x * blockDim.x + threadIdx.x) >> 6;
  const int lane = threadIdx.x & 63;
  if (wid >= N_NODES) return;
  const float di = dinv[wid];
  float4 acc = *reinterpret_cast<const float4*>(&xw[wid * DIM + lane * 4]);
  const float sc = di * di;  // self loop
  acc.x *= sc; acc.y *= sc; acc.z *= sc; acc.w *= sc;
  const int e0 = row_start[wid], e1 = row_start[wid + 1];
  for (int e = e0; e < e1; ++e) {
    int s = colidx[e];
    float nrm = dinv[s] * di;
    float4 v = *reinterpret_cast<const float4*>(&xw[s * DIM + lane * 4]);
    acc.x += v.x * nrm; acc.y += v.y * nrm;
    acc.z += v.z * nrm; acc.w += v.w * nrm;
  }
  float4 b4 = *reinterpret_cast<const float4*>(&bias[lane * 4]);
  acc.x += b4.x; acc.y += b4.y; acc.z += b4.z; acc.w += b4.w;
  const float a0 = slope[0];
  acc.x = acc.x >= 0.f ? acc.x : a0 * acc.x;
  acc.y = acc.y >= 0.f ? acc.y : a0 * acc.y;
  acc.z = acc.z >= 0.f ? acc.z : a0 * acc.z;
  acc.w = acc.w >= 0.f ? acc.w : a0 * acc.w;
  *reinterpret_cast<float4*>(&z1[wid * DIM + lane * 4]) = acc;
}

// z2 aggregation fused with neg = z2 @ wsum (z2 never materialized)
__global__ __launch_bounds__(256) void k_agg2_neg(
    const float* __restrict__ xw, const int* __restrict__ row_start,
    const int* __restrict__ colidx, const int* __restrict__ perm,
    const float* __restrict__ dinv, const float* __restrict__ bias,
    const float* __restrict__ slope, const float* __restrict__ wsum,
    float* __restrict__ neg) {
  const int wid = (blockIdx.x * blockDim.x + threadIdx.x) >> 6;
  const int lane = threadIdx.x & 63;
  if (wid >= N_NODES) return;
  const float di = dinv[wid];
  int pi = perm[wid];
  float4 acc = *reinterpret_cast<const float4*>(&xw[pi * DIM + lane * 4]);
  const float sc = di * di;
  acc.x *= sc; acc.y *= sc; acc.z *= sc; acc.w *= sc;
  const int e0 = row_start[wid], e1 = row_start[wid + 1];
  for (int e = e0; e < e1; ++e) {
    int s = colidx[e];
    float nrm = dinv[s] * di;
    int ps = perm[s];
    float4 v = *reinterpret_cast<const float4*>(&xw[ps * DIM + lane * 4]);
    acc.x += v.x * nrm; acc.y += v.y * nrm;
    acc.z += v.z * nrm; acc.w += v.w * nrm;
  }
  float4 b4 = *reinterpret_cast<const float4*>(&bias[lane * 4]);
  acc.x += b4.x; acc.y += b4.y; acc.z += b4.z; acc.w += b4.w;
  const float a0 = slope[0];
  acc.x = acc.x >= 0.f ? acc.x : a0 * acc.x;
  acc.y = acc.y >= 0.f ? acc.y : a0 * acc.y;
  acc.z = acc.z >= 0.f ? acc.z : a0 * acc.z;
  acc.w = acc.w >= 0.f ? acc.w : a0 * acc.w;
  float4 w4 = *reinterpret_cast<const float4*>(&wsum[lane * 4]);
  float d = acc.x * w4.x + acc.y * w4.y + acc.z * w4.z + acc.w * w4.w;
#pragma unroll
  for (int off = 32; off > 0; off >>= 1) d += __shfl_down(d, off);
  if (lane == 0) neg[wid] = d;
}

// ---------------- summary / wsum / pos ----------------

__global__ void k_colsum(const float* __restrict__ z1, float* __restrict__ colsum) {
  const int col = threadIdx.x;  // 256 threads = 256 cols
  float s = 0.f;
  for (int r = blockIdx.x; r < N_NODES; r += gridDim.x) s += z1[r * DIM + col];
  atomicAdd(&colsum[col], s);
}

__global__ void k_wsum(const float* __restrict__ colsum,
                       const float* __restrict__ disc_W,
                       float* __restrict__ wsum) {
  __shared__ float s[DIM];
  const int t = threadIdx.x;
  float m = colsum[t] * (1.0f / (float)N_NODES);
  s[t] = 1.0f / (1.0f + expf(-m));
  __syncthreads();
  float acc = 0.f;
  for (int j = 0; j < DIM; ++j) acc += disc_W[t * DIM + j] * s[j];
  wsum[t] = acc;
}

__global__ __launch_bounds__(256) void k_pos(const float* __restrict__ z1,
                                             const float* __restrict__ wsum,
                                             float* __restrict__ pos) {
  const int wid = (blockIdx.x * blockDim.x + threadIdx.x) >> 6;
  const int lane = threadIdx.x & 63;
  if (wid >= N_NODES) return;
  float4 v = *reinterpret_cast<const float4*>(&z1[wid * DIM + lane * 4]);
  float4 w4 = *reinterpret_cast<const float4*>(&wsum[lane * 4]);
  float d = v.x * w4.x + v.y * w4.y + v.z * w4.z + v.w * w4.w;
#pragma unroll
  for (int off = 32; off > 0; off >>= 1) d += __shfl_down(d, off);
  if (lane == 0) pos[wid] = d;
}

// ---------------- launch ----------------

extern "C" void kernel_launch(void* const* d_in, const int* in_sizes, int n_in,
                              void* d_out, int out_size, void* d_ws, size_t ws_size,
                              hipStream_t stream) {
  const float* x      = (const float*)d_in[0];
  const float* W      = (const float*)d_in[1];
  const float* b      = (const float*)d_in[2];
  const float* a      = (const float*)d_in[3];
  const float* disc_W = (const float*)d_in[4];
  const int*   eidx   = (const int*)d_in[5];
  const int*   perm   = (const int*)d_in[6];
  const int* src = eidx;
  const int* dst = eidx + N_EDGES;

  constexpr size_t SZ_MAT  = (size_t)N_NODES * DIM * sizeof(float);  // 51.2 MB
  constexpr size_t OFF_XW  = 0;
  constexpr size_t OFF_Z1  = OFF_XW + SZ_MAT;
  constexpr size_t OFF_DEG = OFF_Z1 + SZ_MAT;
  constexpr size_t OFF_DNV = OFF_DEG + 200192;
  constexpr size_t OFF_RS  = OFF_DNV + 200192;
  constexpr size_t OFF_CUR = OFF_RS + 200448;
  constexpr size_t OFF_CI  = OFF_CUR + 200192;
  constexpr size_t OFF_CS  = OFF_CI + (size_t)N_EDGES * 4;
  constexpr size_t OFF_WSM = OFF_CS + 1024;
  constexpr size_t NEED    = OFF_WSM + 1024;
  if (ws_size < NEED) return;  // workspace too small: fail validation cleanly

  char* ws = (char*)d_ws;
  float* xw     = (float*)(ws + OFF_XW);
  float* z1     = (float*)(ws + OFF_Z1);
  int*   deg    = (int*)(ws + OFF_DEG);
  float* dinv   = (float*)(ws + OFF_DNV);
  int*   rowst  = (int*)(ws + OFF_RS);
  int*   cursor = (int*)(ws + OFF_CUR);
  int*   colidx = (int*)(ws + OFF_CI);
  float* colsum = (float*)(ws + OFF_CS);
  float* wsum   = (float*)(ws + OFF_WSM);

  float* pos = (float*)d_out;
  float* neg = pos + N_NODES;

  hipMemsetAsync(deg, 0, N_NODES * sizeof(int), stream);
  hipMemsetAsync(colsum, 0, DIM * sizeof(float), stream);

  k_deg<<<(N_EDGES + 255) / 256, 256, 0, stream>>>(dst, deg);
  k_dinv<<<(N_NODES + 255) / 256, 256, 0, stream>>>(deg, dinv);
  k_scan<<<1, 1024, 0, stream>>>(deg, rowst, cursor);
  k_scatter<<<(N_EDGES + 255) / 256, 256, 0, stream>>>(src, dst, cursor, colidx);

  k_gemm<<<(N_NODES + 63) / 64, 256, 0, stream>>>(x, W, xw);

  k_agg1<<<(N_NODES * 64 + 255) / 256, 256, 0, stream>>>(
      xw, rowst, colidx, dinv, b, a, z1);
  k_colsum<<<128, 256, 0, stream>>>(z1, colsum);
  k_wsum<<<1, 256, 0, stream>>>(colsum, disc_W, wsum);

  k_pos<<<(N_NODES * 64 + 255) / 256, 256, 0, stream>>>(z1, wsum, pos);
  k_agg2_neg<<<(N_NODES * 64 + 255) / 256, 256, 0, stream>>>(
      xw, rowst, colidx, perm, dinv, b, a, wsum, neg);
}

// Round 2
// 462.749 us; speedup vs baseline: 1.5173x; 1.5173x over previous
//
#include <hip/hip_runtime.h>

#define N_NODES 50000
#define N_EDGES 800000
#define DIM 256

typedef __attribute__((ext_vector_type(8))) short bf16x8;
typedef __attribute__((ext_vector_type(4))) float f32x4;

// ---- bf16 helpers (RNE) ----
__device__ __forceinline__ unsigned int f2bf(float f) {
  unsigned int u = __float_as_uint(f);
  return (u + 0x7FFFu + ((u >> 16) & 1u)) >> 16;  // low 16 bits valid
}
__device__ __forceinline__ float bf_lo(unsigned int u) {
  return __uint_as_float(u << 16);
}
__device__ __forceinline__ float bf_hi(unsigned int u) {
  return __uint_as_float(u & 0xFFFF0000u);
}

// ---------------- CSR build ----------------

__global__ void k_deg(const int* __restrict__ dst, int* __restrict__ deg) {
  int e = blockIdx.x * blockDim.x + threadIdx.x;
  if (e < N_EDGES) atomicAdd(&deg[dst[e]], 1);
}

__global__ void k_dinv(const int* __restrict__ deg, float* __restrict__ dinv) {
  int i = blockIdx.x * blockDim.x + threadIdx.x;
  if (i < N_NODES) dinv[i] = rsqrtf((float)(deg[i] + 1));  // +1 self-loop
}

__global__ __launch_bounds__(1024) void k_scan(const int* __restrict__ deg,
                                               int* __restrict__ row_start,
                                               int* __restrict__ cursor) {
  __shared__ int sums[1024];
  const int t = threadIdx.x;
  const int CH = (N_NODES + 1023) / 1024;  // 49
  int begin = t * CH;
  int end = begin + CH; if (end > N_NODES) end = N_NODES;
  int s = 0;
  for (int i = begin; i < end; ++i) s += deg[i];
  sums[t] = s;
  __syncthreads();
  for (int off = 1; off < 1024; off <<= 1) {
    int v = (t >= off) ? sums[t - off] : 0;
    __syncthreads();
    sums[t] += v;
    __syncthreads();
  }
  int run = sums[t] - s;  // exclusive prefix
  for (int i = begin; i < end; ++i) {
    row_start[i] = run;
    cursor[i] = run;
    run += deg[i];
  }
  if (t == 1023) row_start[N_NODES] = sums[1023];
}

// scatter: also precompute permuted src index and edge norm
__global__ void k_scatter(const int* __restrict__ src, const int* __restrict__ dst,
                          const int* __restrict__ perm, const float* __restrict__ dinv,
                          int* __restrict__ cursor, int* __restrict__ colidx,
                          int* __restrict__ colidx2, float* __restrict__ colnorm) {
  int e = blockIdx.x * blockDim.x + threadIdx.x;
  if (e < N_EDGES) {
    int s = src[e], d = dst[e];
    int p = atomicAdd(&cursor[d], 1);
    colidx[p] = s;
    colidx2[p] = perm[s];
    colnorm[p] = dinv[s] * dinv[d];
  }
}

// ---------------- W transpose + bf16 convert: Wt[n][k] ----------------

__global__ void k_prep(const float* __restrict__ W, ushort* __restrict__ Wt) {
  int n = blockIdx.x, k = threadIdx.x;
  Wt[n * DIM + k] = (ushort)f2bf(W[k * DIM + n]);
}

// ---------------- GEMM: XW = X @ W (bf16 MFMA, out bf16) ----------------
// Block tile 128(m) x 256(n), BK=32, 8 waves (2m x 4n), wave tile 64x64.
// Operand roles swapped: A = Wt fragment (rows=n), B = X fragment (cols=m)
// so D col = m, D rows(regs) = 4 consecutive n -> packed bf16x4 stores.
// LDS row stride 40 ushorts (80B) -> b128 reads are 2-way (free).

__global__ __launch_bounds__(512) void k_gemm(const float* __restrict__ X,
                                              const ushort* __restrict__ Wt,
                                              ushort* __restrict__ XW) {
  __shared__ ushort Xs[128 * 40];
  __shared__ ushort Ws[256 * 40];
  const int tid = threadIdx.x;
  const int lane = tid & 63;
  const int w = tid >> 6;
  const int wm = w >> 2, wn = w & 3;
  const int m0 = blockIdx.x * 128;
  const int l16 = lane & 15, kh = lane >> 4;

  f32x4 acc[4][4];
#pragma unroll
  for (int mf = 0; mf < 4; ++mf)
#pragma unroll
    for (int nf = 0; nf < 4; ++nf) acc[mf][nf] = (f32x4){0.f, 0.f, 0.f, 0.f};

  for (int k0 = 0; k0 < DIM; k0 += 32) {
    // stage X tile (f32 -> bf16 in regs)
#pragma unroll
    for (int it = 0; it < 2; ++it) {
      int idx = tid + it * 512;
      int row = idx >> 3, q = idx & 7;
      int grow = m0 + row;
      float4 v = make_float4(0.f, 0.f, 0.f, 0.f);
      if (grow < N_NODES)
        v = *reinterpret_cast<const float4*>(&X[(size_t)grow * DIM + k0 + q * 4]);
      uint2 p;
      p.x = f2bf(v.x) | (f2bf(v.y) << 16);
      p.y = f2bf(v.z) | (f2bf(v.w) << 16);
      *reinterpret_cast<uint2*>(&Xs[row * 40 + q * 4]) = p;
    }
    // stage Wt tile (already bf16, 16B chunks)
#pragma unroll
    for (int it = 0; it < 2; ++it) {
      int idx = tid + it * 512;
      int n = idx >> 2, c = idx & 3;
      uint4 wv = *reinterpret_cast<const uint4*>(&Wt[n * DIM + k0 + c * 8]);
      *reinterpret_cast<uint4*>(&Ws[n * 40 + c * 8]) = wv;
    }
    __syncthreads();
    bf16x8 a[4], b[4];
#pragma unroll
    for (int f = 0; f < 4; ++f) {
      a[f] = *reinterpret_cast<const bf16x8*>(&Ws[(wn * 64 + f * 16 + l16) * 40 + kh * 8]);
      b[f] = *reinterpret_cast<const bf16x8*>(&Xs[(wm * 64 + f * 16 + l16) * 40 + kh * 8]);
    }
#pragma unroll
    for (int mf = 0; mf < 4; ++mf)
#pragma unroll
      for (int nf = 0; nf < 4; ++nf)
        acc[mf][nf] = __builtin_amdgcn_mfma_f32_16x16x32_bf16(a[nf], b[mf],
                                                              acc[mf][nf], 0, 0, 0);
    __syncthreads();
  }
  // epilogue: D col = m (lane&15), D rows = n (kh*4 + reg)
#pragma unroll
  for (int mf = 0; mf < 4; ++mf) {
    int m = m0 + wm * 64 + mf * 16 + l16;
    if (m >= N_NODES) continue;
#pragma unroll
    for (int nf = 0; nf < 4; ++nf) {
      int nb = wn * 64 + nf * 16 + kh * 4;
      uint2 p;
      p.x = f2bf(acc[mf][nf][0]) | (f2bf(acc[mf][nf][1]) << 16);
      p.y = f2bf(acc[mf][nf][2]) | (f2bf(acc[mf][nf][3]) << 16);
      *reinterpret_cast<uint2*>(&XW[(size_t)m * DIM + nb]) = p;
    }
  }
}

// ---------------- aggregation: one wave per dst row, bf16 rows ----------------

__device__ __forceinline__ void acc_row(const ushort* __restrict__ xw, int s,
                                        int lane, float nrm,
                                        float& ax, float& ay, float& az, float& aw) {
  uint2 v = *reinterpret_cast<const uint2*>(xw + (size_t)s * DIM + lane * 4);
  ax = fmaf(bf_lo(v.x), nrm, ax);
  ay = fmaf(bf_hi(v.x), nrm, ay);
  az = fmaf(bf_lo(v.y), nrm, az);
  aw = fmaf(bf_hi(v.y), nrm, aw);
}

__global__ __launch_bounds__(256) void k_agg1(
    const ushort* __restrict__ xw, const int* __restrict__ row_start,
    const int* __restrict__ colidx, const float* __restrict__ colnorm,
    const float* __restrict__ dinv, const float* __restrict__ bias,
    const float* __restrict__ slope, ushort* __restrict__ z1) {
  const int wid = (blockIdx.x * blockDim.x + threadIdx.x) >> 6;
  const int lane = threadIdx.x & 63;
  if (wid >= N_NODES) return;
  const float di = dinv[wid];
  float ax = 0.f, ay = 0.f, az = 0.f, aw = 0.f;
  acc_row(xw, wid, lane, di * di, ax, ay, az, aw);  // self loop
  const int e0 = row_start[wid], e1 = row_start[wid + 1];
  int e = e0;
  for (; e + 4 <= e1; e += 4) {
    int s0 = colidx[e + 0], s1 = colidx[e + 1], s2 = colidx[e + 2], s3 = colidx[e + 3];
    float n0 = colnorm[e + 0], n1 = colnorm[e + 1], n2 = colnorm[e + 2], n3 = colnorm[e + 3];
    uint2 v0 = *reinterpret_cast<const uint2*>(xw + (size_t)s0 * DIM + lane * 4);
    uint2 v1 = *reinterpret_cast<const uint2*>(xw + (size_t)s1 * DIM + lane * 4);
    uint2 v2 = *reinterpret_cast<const uint2*>(xw + (size_t)s2 * DIM + lane * 4);
    uint2 v3 = *reinterpret_cast<const uint2*>(xw + (size_t)s3 * DIM + lane * 4);
    ax = fmaf(bf_lo(v0.x), n0, ax); ay = fmaf(bf_hi(v0.x), n0, ay);
    az = fmaf(bf_lo(v0.y), n0, az); aw = fmaf(bf_hi(v0.y), n0, aw);
    ax = fmaf(bf_lo(v1.x), n1, ax); ay = fmaf(bf_hi(v1.x), n1, ay);
    az = fmaf(bf_lo(v1.y), n1, az); aw = fmaf(bf_hi(v1.y), n1, aw);
    ax = fmaf(bf_lo(v2.x), n2, ax); ay = fmaf(bf_hi(v2.x), n2, ay);
    az = fmaf(bf_lo(v2.y), n2, az); aw = fmaf(bf_hi(v2.y), n2, aw);
    ax = fmaf(bf_lo(v3.x), n3, ax); ay = fmaf(bf_hi(v3.x), n3, ay);
    az = fmaf(bf_lo(v3.y), n3, az); aw = fmaf(bf_hi(v3.y), n3, aw);
  }
  for (; e < e1; ++e)
    acc_row(xw, colidx[e], lane, colnorm[e], ax, ay, az, aw);
  float4 b4 = *reinterpret_cast<const float4*>(&bias[lane * 4]);
  ax += b4.x; ay += b4.y; az += b4.z; aw += b4.w;
  const float a0 = slope[0];
  ax = ax >= 0.f ? ax : a0 * ax;
  ay = ay >= 0.f ? ay : a0 * ay;
  az = az >= 0.f ? az : a0 * az;
  aw = aw >= 0.f ? aw : a0 * aw;
  uint2 p;
  p.x = f2bf(ax) | (f2bf(ay) << 16);
  p.y = f2bf(az) | (f2bf(aw) << 16);
  *reinterpret_cast<uint2*>(z1 + (size_t)wid * DIM + lane * 4) = p;
}

// z2 aggregation fused with neg = z2 @ wsum (z2 never materialized)
__global__ __launch_bounds__(256) void k_agg2_neg(
    const ushort* __restrict__ xw, const int* __restrict__ row_start,
    const int* __restrict__ colidx2, const float* __restrict__ colnorm,
    const int* __restrict__ perm, const float* __restrict__ dinv,
    const float* __restrict__ bias, const float* __restrict__ slope,
    const float* __restrict__ wsum, float* __restrict__ neg) {
  const int wid = (blockIdx.x * blockDim.x + threadIdx.x) >> 6;
  const int lane = threadIdx.x & 63;
  if (wid >= N_NODES) return;
  const float di = dinv[wid];
  float ax = 0.f, ay = 0.f, az = 0.f, aw = 0.f;
  acc_row(xw, perm[wid], lane, di * di, ax, ay, az, aw);  // self loop (permuted)
  const int e0 = row_start[wid], e1 = row_start[wid + 1];
  int e = e0;
  for (; e + 4 <= e1; e += 4) {
    int s0 = colidx2[e + 0], s1 = colidx2[e + 1], s2 = colidx2[e + 2], s3 = colidx2[e + 3];
    float n0 = colnorm[e + 0], n1 = colnorm[e + 1], n2 = colnorm[e + 2], n3 = colnorm[e + 3];
    uint2 v0 = *reinterpret_cast<const uint2*>(xw + (size_t)s0 * DIM + lane * 4);
    uint2 v1 = *reinterpret_cast<const uint2*>(xw + (size_t)s1 * DIM + lane * 4);
    uint2 v2 = *reinterpret_cast<const uint2*>(xw + (size_t)s2 * DIM + lane * 4);
    uint2 v3 = *reinterpret_cast<const uint2*>(xw + (size_t)s3 * DIM + lane * 4);
    ax = fmaf(bf_lo(v0.x), n0, ax); ay = fmaf(bf_hi(v0.x), n0, ay);
    az = fmaf(bf_lo(v0.y), n0, az); aw = fmaf(bf_hi(v0.y), n0, aw);
    ax = fmaf(bf_lo(v1.x), n1, ax); ay = fmaf(bf_hi(v1.x), n1, ay);
    az = fmaf(bf_lo(v1.y), n1, az); aw = fmaf(bf_hi(v1.y), n1, aw);
    ax = fmaf(bf_lo(v2.x), n2, ax); ay = fmaf(bf_hi(v2.x), n2, ay);
    az = fmaf(bf_lo(v2.y), n2, az); aw = fmaf(bf_hi(v2.y), n2, aw);
    ax = fmaf(bf_lo(v3.x), n3, ax); ay = fmaf(bf_hi(v3.x), n3, ay);
    az = fmaf(bf_lo(v3.y), n3, az); aw = fmaf(bf_hi(v3.y), n3, aw);
  }
  for (; e < e1; ++e)
    acc_row(xw, colidx2[e], lane, colnorm[e], ax, ay, az, aw);
  float4 b4 = *reinterpret_cast<const float4*>(&bias[lane * 4]);
  ax += b4.x; ay += b4.y; az += b4.z; aw += b4.w;
  const float a0 = slope[0];
  ax = ax >= 0.f ? ax : a0 * ax;
  ay = ay >= 0.f ? ay : a0 * ay;
  az = az >= 0.f ? az : a0 * az;
  aw = aw >= 0.f ? aw : a0 * aw;
  float4 w4 = *reinterpret_cast<const float4*>(&wsum[lane * 4]);
  float d = ax * w4.x + ay * w4.y + az * w4.z + aw * w4.w;
#pragma unroll
  for (int off = 32; off > 0; off >>= 1) d += __shfl_down(d, off);
  if (lane == 0) neg[wid] = d;
}

// ---------------- summary / wsum / pos ----------------

__global__ __launch_bounds__(256) void k_colsum(const ushort* __restrict__ z1,
                                                float* __restrict__ colsum) {
  __shared__ float red[256];
  const int t = threadIdx.x;
  const int cid = t & 31;           // col chunk of 8
  const int r0 = blockIdx.x * 8 + (t >> 5);
  float s[8] = {0.f, 0.f, 0.f, 0.f, 0.f, 0.f, 0.f, 0.f};
  for (int r = r0; r < N_NODES; r += 8 * 512) {
    uint4 v = *reinterpret_cast<const uint4*>(z1 + (size_t)r * DIM + cid * 8);
    s[0] += bf_lo(v.x); s[1] += bf_hi(v.x);
    s[2] += bf_lo(v.y); s[3] += bf_hi(v.y);
    s[4] += bf_lo(v.z); s[5] += bf_hi(v.z);
    s[6] += bf_lo(v.w); s[7] += bf_hi(v.w);
  }
#pragma unroll
  for (int j = 0; j < 8; ++j) {
    red[t] = s[j];
    __syncthreads();
    if (t < 32) {
      float tot = red[t] + red[t + 32] + red[t + 64] + red[t + 96] +
                  red[t + 128] + red[t + 160] + red[t + 192] + red[t + 224];
      atomicAdd(&colsum[t * 8 + j], tot);
    }
    __syncthreads();
  }
}

__global__ void k_wsum(const float* __restrict__ colsum,
                       const float* __restrict__ disc_W,
                       float* __restrict__ wsum) {
  __shared__ float s[DIM];
  const int t = threadIdx.x;
  float m = colsum[t] * (1.0f / (float)N_NODES);
  s[t] = 1.0f / (1.0f + expf(-m));
  __syncthreads();
  float acc = 0.f;
  for (int j = 0; j < DIM; ++j) acc += disc_W[t * DIM + j] * s[j];
  wsum[t] = acc;
}

__global__ __launch_bounds__(256) void k_pos(const ushort* __restrict__ z1,
                                             const float* __restrict__ wsum,
                                             float* __restrict__ pos) {
  const int wid = (blockIdx.x * blockDim.x + threadIdx.x) >> 6;
  const int lane = threadIdx.x & 63;
  if (wid >= N_NODES) return;
  uint2 v = *reinterpret_cast<const uint2*>(z1 + (size_t)wid * DIM + lane * 4);
  float4 w4 = *reinterpret_cast<const float4*>(&wsum[lane * 4]);
  float d = bf_lo(v.x) * w4.x + bf_hi(v.x) * w4.y + bf_lo(v.y) * w4.z + bf_hi(v.y) * w4.w;
#pragma unroll
  for (int off = 32; off > 0; off >>= 1) d += __shfl_down(d, off);
  if (lane == 0) pos[wid] = d;
}

// ---------------- launch ----------------

extern "C" void kernel_launch(void* const* d_in, const int* in_sizes, int n_in,
                              void* d_out, int out_size, void* d_ws, size_t ws_size,
                              hipStream_t stream) {
  const float* x      = (const float*)d_in[0];
  const float* W      = (const float*)d_in[1];
  const float* b      = (const float*)d_in[2];
  const float* a      = (const float*)d_in[3];
  const float* disc_W = (const float*)d_in[4];
  const int*   eidx   = (const int*)d_in[5];
  const int*   perm   = (const int*)d_in[6];
  const int* src = eidx;
  const int* dst = eidx + N_EDGES;

  constexpr size_t SZ_BFM  = (size_t)N_NODES * DIM * 2;  // 25.6 MB
  constexpr size_t OFF_XW  = 0;
  constexpr size_t OFF_Z1  = OFF_XW + SZ_BFM;
  constexpr size_t OFF_WT  = OFF_Z1 + SZ_BFM;
  constexpr size_t OFF_DEG = OFF_WT + 131072;
  constexpr size_t OFF_DNV = OFF_DEG + 200192;
  constexpr size_t OFF_RS  = OFF_DNV + 200192;
  constexpr size_t OFF_CUR = OFF_RS + 200448;
  constexpr size_t OFF_CI  = OFF_CUR + 200192;
  constexpr size_t OFF_CI2 = OFF_CI + (size_t)N_EDGES * 4;
  constexpr size_t OFF_CN  = OFF_CI2 + (size_t)N_EDGES * 4;
  constexpr size_t OFF_CS  = OFF_CN + (size_t)N_EDGES * 4;
  constexpr size_t OFF_WSM = OFF_CS + 1024;
  constexpr size_t NEED    = OFF_WSM + 1024;
  if (ws_size < NEED) return;

  char* ws = (char*)d_ws;
  ushort* xw     = (ushort*)(ws + OFF_XW);
  ushort* z1     = (ushort*)(ws + OFF_Z1);
  ushort* Wt     = (ushort*)(ws + OFF_WT);
  int*    deg    = (int*)(ws + OFF_DEG);
  float*  dinv   = (float*)(ws + OFF_DNV);
  int*    rowst  = (int*)(ws + OFF_RS);
  int*    cursor = (int*)(ws + OFF_CUR);
  int*    colidx = (int*)(ws + OFF_CI);
  int*    colidx2= (int*)(ws + OFF_CI2);
  float*  colnorm= (float*)(ws + OFF_CN);
  float*  colsum = (float*)(ws + OFF_CS);
  float*  wsum   = (float*)(ws + OFF_WSM);

  float* pos = (float*)d_out;
  float* neg = pos + N_NODES;

  hipMemsetAsync(deg, 0, N_NODES * sizeof(int), stream);
  hipMemsetAsync(colsum, 0, DIM * sizeof(float), stream);

  k_deg<<<(N_EDGES + 255) / 256, 256, 0, stream>>>(dst, deg);
  k_dinv<<<(N_NODES + 255) / 256, 256, 0, stream>>>(deg, dinv);
  k_scan<<<1, 1024, 0, stream>>>(deg, rowst, cursor);
  k_scatter<<<(N_EDGES + 255) / 256, 256, 0, stream>>>(src, dst, perm, dinv,
                                                       cursor, colidx, colidx2, colnorm);

  k_prep<<<DIM, DIM, 0, stream>>>(W, Wt);
  k_gemm<<<(N_NODES + 127) / 128, 512, 0, stream>>>(x, Wt, xw);

  k_agg1<<<(N_NODES * 64 + 255) / 256, 256, 0, stream>>>(
      xw, rowst, colidx, colnorm, dinv, b, a, z1);
  k_colsum<<<512, 256, 0, stream>>>(z1, colsum);
  k_wsum<<<1, 256, 0, stream>>>(colsum, disc_W, wsum);

  k_pos<<<(N_NODES * 64 + 255) / 256, 256, 0, stream>>>(z1, wsum, pos);
  k_agg2_neg<<<(N_NODES * 64 + 255) / 256, 256, 0, stream>>>(
      xw, rowst, colidx2, colnorm, perm, dinv, b, a, wsum, neg);
}

// Round 3
// 364.037 us; speedup vs baseline: 1.9288x; 1.2712x over previous
//
#include <hip/hip_runtime.h>

#define N_NODES 50000
#define N_EDGES 800000
#define DIM 256
#define NB 196  // ceil(N_NODES/256)

typedef __attribute__((ext_vector_type(8))) short bf16x8;
typedef __attribute__((ext_vector_type(4))) float f32x4;

// ---- bf16 helpers (RNE) ----
__device__ __forceinline__ unsigned int f2bf(float f) {
  unsigned int u = __float_as_uint(f);
  return (u + 0x7FFFu + ((u >> 16) & 1u)) >> 16;  // low 16 bits valid
}
__device__ __forceinline__ float bf_lo(unsigned int u) {
  return __uint_as_float(u << 16);
}
__device__ __forceinline__ float bf_hi(unsigned int u) {
  return __uint_as_float(u & 0xFFFF0000u);
}

// ---------------- CSR build ----------------

__global__ void k_deg(const int* __restrict__ dst, int* __restrict__ deg) {
  int e = blockIdx.x * blockDim.x + threadIdx.x;
  if (e < N_EDGES) atomicAdd(&deg[dst[e]], 1);
}

// per-256-chunk degree sums + dinv
__global__ __launch_bounds__(256) void k_bsum(const int* __restrict__ deg,
                                              float* __restrict__ dinv,
                                              int* __restrict__ bsum) {
  __shared__ int red[4];
  const int t = threadIdx.x;
  const int i = blockIdx.x * 256 + t;
  int d = 0;
  if (i < N_NODES) {
    d = deg[i];
    dinv[i] = rsqrtf((float)(d + 1));  // +1 self-loop
  }
  int s = d;
#pragma unroll
  for (int off = 32; off > 0; off >>= 1) s += __shfl_down(s, off);
  if ((t & 63) == 0) red[t >> 6] = s;
  __syncthreads();
  if (t == 0) bsum[blockIdx.x] = red[0] + red[1] + red[2] + red[3];
}

// single small block: exclusive scan of the 196 block sums
__global__ __launch_bounds__(256) void k_bscan(const int* __restrict__ bsum,
                                               int* __restrict__ boff,
                                               int* __restrict__ row_start) {
  __shared__ int s[256];
  const int t = threadIdx.x;
  int v = (t < NB) ? bsum[t] : 0;
  s[t] = v;
  __syncthreads();
  for (int off = 1; off < 256; off <<= 1) {
    int u = (t >= off) ? s[t - off] : 0;
    __syncthreads();
    s[t] += u;
    __syncthreads();
  }
  if (t < NB) boff[t] = s[t] - v;
  if (t == 0) row_start[N_NODES] = N_EDGES;  // total degree == E by construction
}

// per-chunk local exclusive scan + chunk offset
__global__ __launch_bounds__(256) void k_rowstart(const int* __restrict__ deg,
                                                  const int* __restrict__ boff,
                                                  int* __restrict__ row_start,
                                                  int* __restrict__ cursor) {
  __shared__ int s[256];
  const int t = threadIdx.x;
  const int i = blockIdx.x * 256 + t;
  int d = (i < N_NODES) ? deg[i] : 0;
  s[t] = d;
  __syncthreads();
  for (int off = 1; off < 256; off <<= 1) {
    int u = (t >= off) ? s[t - off] : 0;
    __syncthreads();
    s[t] += u;
    __syncthreads();
  }
  if (i < N_NODES) {
    int r = boff[blockIdx.x] + s[t] - d;
    row_start[i] = r;
    cursor[i] = r;
  }
}

// scatter: also precompute permuted src index and edge norm
__global__ void k_scatter(const int* __restrict__ src, const int* __restrict__ dst,
                          const int* __restrict__ perm, const float* __restrict__ dinv,
                          int* __restrict__ cursor, int* __restrict__ colidx,
                          int* __restrict__ colidx2, float* __restrict__ colnorm) {
  int e = blockIdx.x * blockDim.x + threadIdx.x;
  if (e < N_EDGES) {
    int s = src[e], d = dst[e];
    int p = atomicAdd(&cursor[d], 1);
    colidx[p] = s;
    colidx2[p] = perm[s];
    colnorm[p] = dinv[s] * dinv[d];
  }
}

// ---------------- W transpose + bf16 convert: Wt[n][k] ----------------

__global__ void k_prep(const float* __restrict__ W, ushort* __restrict__ Wt) {
  int n = blockIdx.x, k = threadIdx.x;
  Wt[n * DIM + k] = (ushort)f2bf(W[k * DIM + n]);
}

// ---------------- GEMM: XW = X @ W (bf16 MFMA, out bf16) ----------------
// Block tile 128(m) x 256(n), BK=32, 8 waves (2m x 4n), wave tile 64x64.
// Operand roles swapped: A = Wt fragment (rows=n), B = X fragment (cols=m)
// so D col = m, D rows(regs) = 4 consecutive n -> packed bf16x4 stores.
// LDS row stride 40 ushorts (80B) -> b128 reads are 2-way (free).

__global__ __launch_bounds__(512) void k_gemm(const float* __restrict__ X,
                                              const ushort* __restrict__ Wt,
                                              ushort* __restrict__ XW) {
  __shared__ ushort Xs[128 * 40];
  __shared__ ushort Ws[256 * 40];
  const int tid = threadIdx.x;
  const int lane = tid & 63;
  const int w = tid >> 6;
  const int wm = w >> 2, wn = w & 3;
  const int m0 = blockIdx.x * 128;
  const int l16 = lane & 15, kh = lane >> 4;

  f32x4 acc[4][4];
#pragma unroll
  for (int mf = 0; mf < 4; ++mf)
#pragma unroll
    for (int nf = 0; nf < 4; ++nf) acc[mf][nf] = (f32x4){0.f, 0.f, 0.f, 0.f};

  for (int k0 = 0; k0 < DIM; k0 += 32) {
    // stage X tile (f32 -> bf16 in regs)
#pragma unroll
    for (int it = 0; it < 2; ++it) {
      int idx = tid + it * 512;
      int row = idx >> 3, q = idx & 7;
      int grow = m0 + row;
      float4 v = make_float4(0.f, 0.f, 0.f, 0.f);
      if (grow < N_NODES)
        v = *reinterpret_cast<const float4*>(&X[(size_t)grow * DIM + k0 + q * 4]);
      uint2 p;
      p.x = f2bf(v.x) | (f2bf(v.y) << 16);
      p.y = f2bf(v.z) | (f2bf(v.w) << 16);
      *reinterpret_cast<uint2*>(&Xs[row * 40 + q * 4]) = p;
    }
    // stage Wt tile (already bf16, 16B chunks)
#pragma unroll
    for (int it = 0; it < 2; ++it) {
      int idx = tid + it * 512;
      int n = idx >> 2, c = idx & 3;
      uint4 wv = *reinterpret_cast<const uint4*>(&Wt[n * DIM + k0 + c * 8]);
      *reinterpret_cast<uint4*>(&Ws[n * 40 + c * 8]) = wv;
    }
    __syncthreads();
    bf16x8 a[4], b[4];
#pragma unroll
    for (int f = 0; f < 4; ++f) {
      a[f] = *reinterpret_cast<const bf16x8*>(&Ws[(wn * 64 + f * 16 + l16) * 40 + kh * 8]);
      b[f] = *reinterpret_cast<const bf16x8*>(&Xs[(wm * 64 + f * 16 + l16) * 40 + kh * 8]);
    }
#pragma unroll
    for (int mf = 0; mf < 4; ++mf)
#pragma unroll
      for (int nf = 0; nf < 4; ++nf)
        acc[mf][nf] = __builtin_amdgcn_mfma_f32_16x16x32_bf16(a[nf], b[mf],
                                                              acc[mf][nf], 0, 0, 0);
    __syncthreads();
  }
  // epilogue: D col = m (lane&15), D rows = n (kh*4 + reg)
#pragma unroll
  for (int mf = 0; mf < 4; ++mf) {
    int m = m0 + wm * 64 + mf * 16 + l16;
    if (m >= N_NODES) continue;
#pragma unroll
    for (int nf = 0; nf < 4; ++nf) {
      int nb = wn * 64 + nf * 16 + kh * 4;
      uint2 p;
      p.x = f2bf(acc[mf][nf][0]) | (f2bf(acc[mf][nf][1]) << 16);
      p.y = f2bf(acc[mf][nf][2]) | (f2bf(acc[mf][nf][3]) << 16);
      *reinterpret_cast<uint2*>(&XW[(size_t)m * DIM + nb]) = p;
    }
  }
}

// ---------------- aggregation: one wave per dst row, bf16 rows ----------------

__device__ __forceinline__ void acc_row(const ushort* __restrict__ xw, int s,
                                        int lane, float nrm,
                                        float& ax, float& ay, float& az, float& aw) {
  uint2 v = *reinterpret_cast<const uint2*>(xw + (size_t)s * DIM + lane * 4);
  ax = fmaf(bf_lo(v.x), nrm, ax);
  ay = fmaf(bf_hi(v.x), nrm, ay);
  az = fmaf(bf_lo(v.y), nrm, az);
  aw = fmaf(bf_hi(v.y), nrm, aw);
}

// 8-deep unrolled gather-accumulate over CSR range
__device__ __forceinline__ void agg_loop(const ushort* __restrict__ xw,
                                         const int* __restrict__ cidx,
                                         const float* __restrict__ cn,
                                         int e0, int e1, int lane,
                                         float& ax, float& ay, float& az, float& aw) {
  int e = e0;
  for (; e + 8 <= e1; e += 8) {
    uint2 v[8];
    float nn[8];
#pragma unroll
    for (int j = 0; j < 8; ++j) {
      int s = cidx[e + j];
      nn[j] = cn[e + j];
      v[j] = *reinterpret_cast<const uint2*>(xw + (size_t)s * DIM + lane * 4);
    }
#pragma unroll
    for (int j = 0; j < 8; ++j) {
      ax = fmaf(bf_lo(v[j].x), nn[j], ax);
      ay = fmaf(bf_hi(v[j].x), nn[j], ay);
      az = fmaf(bf_lo(v[j].y), nn[j], az);
      aw = fmaf(bf_hi(v[j].y), nn[j], aw);
    }
  }
  for (; e < e1; ++e) acc_row(xw, cidx[e], lane, cn[e], ax, ay, az, aw);
}

__global__ __launch_bounds__(256) void k_agg1(
    const ushort* __restrict__ xw, const int* __restrict__ row_start,
    const int* __restrict__ colidx, const float* __restrict__ colnorm,
    const float* __restrict__ dinv, const float* __restrict__ bias,
    const float* __restrict__ slope, ushort* __restrict__ z1) {
  const int wid = (blockIdx.x * blockDim.x + threadIdx.x) >> 6;
  const int lane = threadIdx.x & 63;
  if (wid >= N_NODES) return;
  const float di = dinv[wid];
  float ax = 0.f, ay = 0.f, az = 0.f, aw = 0.f;
  acc_row(xw, wid, lane, di * di, ax, ay, az, aw);  // self loop
  agg_loop(xw, colidx, colnorm, row_start[wid], row_start[wid + 1], lane,
           ax, ay, az, aw);
  float4 b4 = *reinterpret_cast<const float4*>(&bias[lane * 4]);
  ax += b4.x; ay += b4.y; az += b4.z; aw += b4.w;
  const float a0 = slope[0];
  ax = ax >= 0.f ? ax : a0 * ax;
  ay = ay >= 0.f ? ay : a0 * ay;
  az = az >= 0.f ? az : a0 * az;
  aw = aw >= 0.f ? aw : a0 * aw;
  uint2 p;
  p.x = f2bf(ax) | (f2bf(ay) << 16);
  p.y = f2bf(az) | (f2bf(aw) << 16);
  *reinterpret_cast<uint2*>(z1 + (size_t)wid * DIM + lane * 4) = p;
}

// z2 aggregation fused with neg = z2 @ wsum (z2 never materialized)
__global__ __launch_bounds__(256) void k_agg2_neg(
    const ushort* __restrict__ xw, const int* __restrict__ row_start,
    const int* __restrict__ colidx2, const float* __restrict__ colnorm,
    const int* __restrict__ perm, const float* __restrict__ dinv,
    const float* __restrict__ bias, const float* __restrict__ slope,
    const float* __restrict__ wsum, float* __restrict__ neg) {
  const int wid = (blockIdx.x * blockDim.x + threadIdx.x) >> 6;
  const int lane = threadIdx.x & 63;
  if (wid >= N_NODES) return;
  const float di = dinv[wid];
  float ax = 0.f, ay = 0.f, az = 0.f, aw = 0.f;
  acc_row(xw, perm[wid], lane, di * di, ax, ay, az, aw);  // self loop (permuted)
  agg_loop(xw, colidx2, colnorm, row_start[wid], row_start[wid + 1], lane,
           ax, ay, az, aw);
  float4 b4 = *reinterpret_cast<const float4*>(&bias[lane * 4]);
  ax += b4.x; ay += b4.y; az += b4.z; aw += b4.w;
  const float a0 = slope[0];
  ax = ax >= 0.f ? ax : a0 * ax;
  ay = ay >= 0.f ? ay : a0 * ay;
  az = az >= 0.f ? az : a0 * az;
  aw = aw >= 0.f ? aw : a0 * aw;
  float4 w4 = *reinterpret_cast<const float4*>(&wsum[lane * 4]);
  float d = ax * w4.x + ay * w4.y + az * w4.z + aw * w4.w;
#pragma unroll
  for (int off = 32; off > 0; off >>= 1) d += __shfl_down(d, off);
  if (lane == 0) neg[wid] = d;
}

// ---------------- summary / wsum / pos ----------------

__global__ __launch_bounds__(256) void k_colsum(const ushort* __restrict__ z1,
                                                float* __restrict__ colsum) {
  __shared__ float red[256];
  const int t = threadIdx.x;
  const int cid = t & 31;           // col chunk of 8
  const int r0 = blockIdx.x * 8 + (t >> 5);
  float s[8] = {0.f, 0.f, 0.f, 0.f, 0.f, 0.f, 0.f, 0.f};
  for (int r = r0; r < N_NODES; r += 8 * 512) {
    uint4 v = *reinterpret_cast<const uint4*>(z1 + (size_t)r * DIM + cid * 8);
    s[0] += bf_lo(v.x); s[1] += bf_hi(v.x);
    s[2] += bf_lo(v.y); s[3] += bf_hi(v.y);
    s[4] += bf_lo(v.z); s[5] += bf_hi(v.z);
    s[6] += bf_lo(v.w); s[7] += bf_hi(v.w);
  }
#pragma unroll
  for (int j = 0; j < 8; ++j) {
    red[t] = s[j];
    __syncthreads();
    if (t < 32) {
      float tot = red[t] + red[t + 32] + red[t + 64] + red[t + 96] +
                  red[t + 128] + red[t + 160] + red[t + 192] + red[t + 224];
      atomicAdd(&colsum[t * 8 + j], tot);
    }
    __syncthreads();
  }
}

__global__ void k_wsum(const float* __restrict__ colsum,
                       const float* __restrict__ disc_W,
                       float* __restrict__ wsum) {
  __shared__ float s[DIM];
  const int t = threadIdx.x;
  float m = colsum[t] * (1.0f / (float)N_NODES);
  s[t] = 1.0f / (1.0f + expf(-m));
  __syncthreads();
  float acc = 0.f;
  for (int j = 0; j < DIM; ++j) acc += disc_W[t * DIM + j] * s[j];
  wsum[t] = acc;
}

__global__ __launch_bounds__(256) void k_pos(const ushort* __restrict__ z1,
                                             const float* __restrict__ wsum,
                                             float* __restrict__ pos) {
  const int wid = (blockIdx.x * blockDim.x + threadIdx.x) >> 6;
  const int lane = threadIdx.x & 63;
  if (wid >= N_NODES) return;
  uint2 v = *reinterpret_cast<const uint2*>(z1 + (size_t)wid * DIM + lane * 4);
  float4 w4 = *reinterpret_cast<const float4*>(&wsum[lane * 4]);
  float d = bf_lo(v.x) * w4.x + bf_hi(v.x) * w4.y + bf_lo(v.y) * w4.z + bf_hi(v.y) * w4.w;
#pragma unroll
  for (int off = 32; off > 0; off >>= 1) d += __shfl_down(d, off);
  if (lane == 0) pos[wid] = d;
}

// ---------------- launch ----------------

extern "C" void kernel_launch(void* const* d_in, const int* in_sizes, int n_in,
                              void* d_out, int out_size, void* d_ws, size_t ws_size,
                              hipStream_t stream) {
  const float* x      = (const float*)d_in[0];
  const float* W      = (const float*)d_in[1];
  const float* b      = (const float*)d_in[2];
  const float* a      = (const float*)d_in[3];
  const float* disc_W = (const float*)d_in[4];
  const int*   eidx   = (const int*)d_in[5];
  const int*   perm   = (const int*)d_in[6];
  const int* src = eidx;
  const int* dst = eidx + N_EDGES;

  constexpr size_t SZ_BFM  = (size_t)N_NODES * DIM * 2;  // 25.6 MB
  constexpr size_t OFF_XW  = 0;
  constexpr size_t OFF_Z1  = OFF_XW + SZ_BFM;
  constexpr size_t OFF_WT  = OFF_Z1 + SZ_BFM;
  constexpr size_t OFF_DEG = OFF_WT + 131072;
  constexpr size_t OFF_DNV = OFF_DEG + 200192;
  constexpr size_t OFF_RS  = OFF_DNV + 200192;
  constexpr size_t OFF_CUR = OFF_RS + 200448;
  constexpr size_t OFF_CI  = OFF_CUR + 200192;
  constexpr size_t OFF_CI2 = OFF_CI + (size_t)N_EDGES * 4;
  constexpr size_t OFF_CN  = OFF_CI2 + (size_t)N_EDGES * 4;
  constexpr size_t OFF_CS  = OFF_CN + (size_t)N_EDGES * 4;
  constexpr size_t OFF_WSM = OFF_CS + 1024;
  constexpr size_t OFF_BS  = OFF_WSM + 1024;
  constexpr size_t OFF_BO  = OFF_BS + 1024;
  constexpr size_t NEED    = OFF_BO + 1024;
  if (ws_size < NEED) return;

  char* ws = (char*)d_ws;
  ushort* xw     = (ushort*)(ws + OFF_XW);
  ushort* z1     = (ushort*)(ws + OFF_Z1);
  ushort* Wt     = (ushort*)(ws + OFF_WT);
  int*    deg    = (int*)(ws + OFF_DEG);
  float*  dinv   = (float*)(ws + OFF_DNV);
  int*    rowst  = (int*)(ws + OFF_RS);
  int*    cursor = (int*)(ws + OFF_CUR);
  int*    colidx = (int*)(ws + OFF_CI);
  int*    colidx2= (int*)(ws + OFF_CI2);
  float*  colnorm= (float*)(ws + OFF_CN);
  float*  colsum = (float*)(ws + OFF_CS);
  float*  wsum   = (float*)(ws + OFF_WSM);
  int*    bsum   = (int*)(ws + OFF_BS);
  int*    boff   = (int*)(ws + OFF_BO);

  float* pos = (float*)d_out;
  float* neg = pos + N_NODES;

  hipMemsetAsync(deg, 0, N_NODES * sizeof(int), stream);
  hipMemsetAsync(colsum, 0, DIM * sizeof(float), stream);

  k_deg<<<(N_EDGES + 255) / 256, 256, 0, stream>>>(dst, deg);
  k_bsum<<<NB, 256, 0, stream>>>(deg, dinv, bsum);
  k_bscan<<<1, 256, 0, stream>>>(bsum, boff, rowst);
  k_rowstart<<<NB, 256, 0, stream>>>(deg, boff, rowst, cursor);
  k_scatter<<<(N_EDGES + 255) / 256, 256, 0, stream>>>(src, dst, perm, dinv,
                                                       cursor, colidx, colidx2, colnorm);

  k_prep<<<DIM, DIM, 0, stream>>>(W, Wt);
  k_gemm<<<(N_NODES + 127) / 128, 512, 0, stream>>>(x, Wt, xw);

  k_agg1<<<(N_NODES * 64 + 255) / 256, 256, 0, stream>>>(
      xw, rowst, colidx, colnorm, dinv, b, a, z1);
  k_colsum<<<512, 256, 0, stream>>>(z1, colsum);
  k_wsum<<<1, 256, 0, stream>>>(colsum, disc_W, wsum);

  k_pos<<<(N_NODES * 64 + 255) / 256, 256, 0, stream>>>(z1, wsum, pos);
  k_agg2_neg<<<(N_NODES * 64 + 255) / 256, 256, 0, stream>>>(
      xw, rowst, colidx2, colnorm, perm, dinv, b, a, wsum, neg);
}

// Round 4
// 278.275 us; speedup vs baseline: 2.5232x; 1.3082x over previous
//
#include <hip/hip_runtime.h>

#define N_NODES 50000
#define N_EDGES 800000
#define DIM 256
#define NB 196    // ceil(N_NODES/256)
#define CSB 512   // colsum stage-1 blocks

typedef __attribute__((ext_vector_type(8))) short bf16x8;
typedef __attribute__((ext_vector_type(4))) float f32x4;

// ---- bf16 helpers (RNE) ----
__device__ __forceinline__ unsigned int f2bf(float f) {
  unsigned int u = __float_as_uint(f);
  return (u + 0x7FFFu + ((u >> 16) & 1u)) >> 16;  // low 16 bits valid
}
__device__ __forceinline__ float bf_lo(unsigned int u) {
  return __uint_as_float(u << 16);
}
__device__ __forceinline__ float bf_hi(unsigned int u) {
  return __uint_as_float(u & 0xFFFF0000u);
}

// ---------------- CSR build ----------------

__global__ void k_deg(const int* __restrict__ dst, int* __restrict__ deg) {
  int e = blockIdx.x * blockDim.x + threadIdx.x;
  if (e < N_EDGES) atomicAdd(&deg[dst[e]], 1);
}

__global__ __launch_bounds__(256) void k_bsum(const int* __restrict__ deg,
                                              float* __restrict__ dinv,
                                              int* __restrict__ bsum) {
  __shared__ int red[4];
  const int t = threadIdx.x;
  const int i = blockIdx.x * 256 + t;
  int d = 0;
  if (i < N_NODES) {
    d = deg[i];
    dinv[i] = rsqrtf((float)(d + 1));  // +1 self-loop
  }
  int s = d;
#pragma unroll
  for (int off = 32; off > 0; off >>= 1) s += __shfl_down(s, off);
  if ((t & 63) == 0) red[t >> 6] = s;
  __syncthreads();
  if (t == 0) bsum[blockIdx.x] = red[0] + red[1] + red[2] + red[3];
}

__global__ __launch_bounds__(256) void k_bscan(const int* __restrict__ bsum,
                                               int* __restrict__ boff,
                                               int* __restrict__ row_start) {
  __shared__ int s[256];
  const int t = threadIdx.x;
  int v = (t < NB) ? bsum[t] : 0;
  s[t] = v;
  __syncthreads();
  for (int off = 1; off < 256; off <<= 1) {
    int u = (t >= off) ? s[t - off] : 0;
    __syncthreads();
    s[t] += u;
    __syncthreads();
  }
  if (t < NB) boff[t] = s[t] - v;
  if (t == 0) row_start[N_NODES] = N_EDGES;
}

__global__ __launch_bounds__(256) void k_rowstart(const int* __restrict__ deg,
                                                  const int* __restrict__ boff,
                                                  int* __restrict__ row_start,
                                                  int* __restrict__ cursor) {
  __shared__ int s[256];
  const int t = threadIdx.x;
  const int i = blockIdx.x * 256 + t;
  int d = (i < N_NODES) ? deg[i] : 0;
  s[t] = d;
  __syncthreads();
  for (int off = 1; off < 256; off <<= 1) {
    int u = (t >= off) ? s[t - off] : 0;
    __syncthreads();
    s[t] += u;
    __syncthreads();
  }
  if (i < N_NODES) {
    int r = boff[blockIdx.x] + s[t] - d;
    row_start[i] = r;
    cursor[i] = r;
  }
}

__global__ void k_scatter(const int* __restrict__ src, const int* __restrict__ dst,
                          const int* __restrict__ perm, const float* __restrict__ dinv,
                          int* __restrict__ cursor, int* __restrict__ colidx,
                          int* __restrict__ colidx2, float* __restrict__ colnorm) {
  int e = blockIdx.x * blockDim.x + threadIdx.x;
  if (e < N_EDGES) {
    int s = src[e], d = dst[e];
    int p = atomicAdd(&cursor[d], 1);
    colidx[p] = s;
    colidx2[p] = perm[s];
    colnorm[p] = dinv[s] * dinv[d];
  }
}

// ---------------- W transpose + bf16 convert: Wt[n][k] ----------------

__global__ void k_prep(const float* __restrict__ W, ushort* __restrict__ Wt) {
  int n = blockIdx.x, k = threadIdx.x;
  Wt[n * DIM + k] = (ushort)f2bf(W[k * DIM + n]);
}

// ---------------- GEMM: XW = X @ W (bf16 MFMA, out bf16) ----------------

__global__ __launch_bounds__(512) void k_gemm(const float* __restrict__ X,
                                              const ushort* __restrict__ Wt,
                                              ushort* __restrict__ XW) {
  __shared__ ushort Xs[128 * 40];
  __shared__ ushort Ws[256 * 40];
  const int tid = threadIdx.x;
  const int lane = tid & 63;
  const int w = tid >> 6;
  const int wm = w >> 2, wn = w & 3;
  const int m0 = blockIdx.x * 128;
  const int l16 = lane & 15, kh = lane >> 4;

  f32x4 acc[4][4];
#pragma unroll
  for (int mf = 0; mf < 4; ++mf)
#pragma unroll
    for (int nf = 0; nf < 4; ++nf) acc[mf][nf] = (f32x4){0.f, 0.f, 0.f, 0.f};

  for (int k0 = 0; k0 < DIM; k0 += 32) {
#pragma unroll
    for (int it = 0; it < 2; ++it) {
      int idx = tid + it * 512;
      int row = idx >> 3, q = idx & 7;
      int grow = m0 + row;
      float4 v = make_float4(0.f, 0.f, 0.f, 0.f);
      if (grow < N_NODES)
        v = *reinterpret_cast<const float4*>(&X[(size_t)grow * DIM + k0 + q * 4]);
      uint2 p;
      p.x = f2bf(v.x) | (f2bf(v.y) << 16);
      p.y = f2bf(v.z) | (f2bf(v.w) << 16);
      *reinterpret_cast<uint2*>(&Xs[row * 40 + q * 4]) = p;
    }
#pragma unroll
    for (int it = 0; it < 2; ++it) {
      int idx = tid + it * 512;
      int n = idx >> 2, c = idx & 3;
      uint4 wv = *reinterpret_cast<const uint4*>(&Wt[n * DIM + k0 + c * 8]);
      *reinterpret_cast<uint4*>(&Ws[n * 40 + c * 8]) = wv;
    }
    __syncthreads();
    bf16x8 a[4], b[4];
#pragma unroll
    for (int f = 0; f < 4; ++f) {
      a[f] = *reinterpret_cast<const bf16x8*>(&Ws[(wn * 64 + f * 16 + l16) * 40 + kh * 8]);
      b[f] = *reinterpret_cast<const bf16x8*>(&Xs[(wm * 64 + f * 16 + l16) * 40 + kh * 8]);
    }
#pragma unroll
    for (int mf = 0; mf < 4; ++mf)
#pragma unroll
      for (int nf = 0; nf < 4; ++nf)
        acc[mf][nf] = __builtin_amdgcn_mfma_f32_16x16x32_bf16(a[nf], b[mf],
                                                              acc[mf][nf], 0, 0, 0);
    __syncthreads();
  }
#pragma unroll
  for (int mf = 0; mf < 4; ++mf) {
    int m = m0 + wm * 64 + mf * 16 + l16;
    if (m >= N_NODES) continue;
#pragma unroll
    for (int nf = 0; nf < 4; ++nf) {
      int nb = wn * 64 + nf * 16 + kh * 4;
      uint2 p;
      p.x = f2bf(acc[mf][nf][0]) | (f2bf(acc[mf][nf][1]) << 16);
      p.y = f2bf(acc[mf][nf][2]) | (f2bf(acc[mf][nf][3]) << 16);
      *reinterpret_cast<uint2*>(&XW[(size_t)m * DIM + nb]) = p;
    }
  }
}

// ---------------- aggregation: 2 rows per wave (half-wave per row) ----------------
// lane = h*32 + c; half h handles row r = 2*wid + h; lane covers cols c*8..c*8+8
// via one uint4 (16B) load per gathered row. 8 edges in flight per half.

struct Acc8 { float a[8]; };

__device__ __forceinline__ void fma8(Acc8& A, uint4 v, float n) {
  A.a[0] = fmaf(bf_lo(v.x), n, A.a[0]);
  A.a[1] = fmaf(bf_hi(v.x), n, A.a[1]);
  A.a[2] = fmaf(bf_lo(v.y), n, A.a[2]);
  A.a[3] = fmaf(bf_hi(v.y), n, A.a[3]);
  A.a[4] = fmaf(bf_lo(v.z), n, A.a[4]);
  A.a[5] = fmaf(bf_hi(v.z), n, A.a[5]);
  A.a[6] = fmaf(bf_lo(v.w), n, A.a[6]);
  A.a[7] = fmaf(bf_hi(v.w), n, A.a[7]);
}

__device__ __forceinline__ void agg_loop2(const ushort* __restrict__ xw,
                                          const int* __restrict__ cidx,
                                          const float* __restrict__ cn,
                                          int e, int eEnd, int c, Acc8& A) {
  for (; e + 8 <= eEnd; e += 8) {
    int s[8]; float nn[8]; uint4 v[8];
#pragma unroll
    for (int j = 0; j < 8; ++j) { s[j] = cidx[e + j]; nn[j] = cn[e + j]; }
#pragma unroll
    for (int j = 0; j < 8; ++j)
      v[j] = *reinterpret_cast<const uint4*>(xw + (size_t)s[j] * DIM + c * 8);
#pragma unroll
    for (int j = 0; j < 8; ++j) fma8(A, v[j], nn[j]);
  }
  for (; e < eEnd; ++e) {
    uint4 v = *reinterpret_cast<const uint4*>(xw + (size_t)cidx[e] * DIM + c * 8);
    fma8(A, v, cn[e]);
  }
}

__device__ __forceinline__ void epilogue8(Acc8& A, const float* __restrict__ bias,
                                          float a0, int c) {
  float4 b0 = *reinterpret_cast<const float4*>(&bias[c * 8]);
  float4 b1 = *reinterpret_cast<const float4*>(&bias[c * 8 + 4]);
  A.a[0] += b0.x; A.a[1] += b0.y; A.a[2] += b0.z; A.a[3] += b0.w;
  A.a[4] += b1.x; A.a[5] += b1.y; A.a[6] += b1.z; A.a[7] += b1.w;
#pragma unroll
  for (int j = 0; j < 8; ++j) A.a[j] = A.a[j] >= 0.f ? A.a[j] : a0 * A.a[j];
}

__global__ __launch_bounds__(256) void k_agg1(
    const ushort* __restrict__ xw, const int* __restrict__ row_start,
    const int* __restrict__ colidx, const float* __restrict__ colnorm,
    const float* __restrict__ dinv, const float* __restrict__ bias,
    const float* __restrict__ slope, ushort* __restrict__ z1) {
  const int wid = (blockIdx.x * blockDim.x + threadIdx.x) >> 6;
  const int lane = threadIdx.x & 63;
  const int h = lane >> 5, c = lane & 31;
  const int r = wid * 2 + h;
  if (r >= N_NODES) return;
  const float di = dinv[r];
  Acc8 A;
#pragma unroll
  for (int j = 0; j < 8; ++j) A.a[j] = 0.f;
  uint4 sv = *reinterpret_cast<const uint4*>(xw + (size_t)r * DIM + c * 8);
  fma8(A, sv, di * di);  // self loop
  agg_loop2(xw, colidx, colnorm, row_start[r], row_start[r + 1], c, A);
  epilogue8(A, bias, slope[0], c);
  uint4 p;
  p.x = f2bf(A.a[0]) | (f2bf(A.a[1]) << 16);
  p.y = f2bf(A.a[2]) | (f2bf(A.a[3]) << 16);
  p.z = f2bf(A.a[4]) | (f2bf(A.a[5]) << 16);
  p.w = f2bf(A.a[6]) | (f2bf(A.a[7]) << 16);
  *reinterpret_cast<uint4*>(z1 + (size_t)r * DIM + c * 8) = p;
}

__global__ __launch_bounds__(256) void k_agg2_neg(
    const ushort* __restrict__ xw, const int* __restrict__ row_start,
    const int* __restrict__ colidx2, const float* __restrict__ colnorm,
    const int* __restrict__ perm, const float* __restrict__ dinv,
    const float* __restrict__ bias, const float* __restrict__ slope,
    const float* __restrict__ wsum, float* __restrict__ neg) {
  const int wid = (blockIdx.x * blockDim.x + threadIdx.x) >> 6;
  const int lane = threadIdx.x & 63;
  const int h = lane >> 5, c = lane & 31;
  const int r = wid * 2 + h;
  if (r >= N_NODES) return;
  const float di = dinv[r];
  Acc8 A;
#pragma unroll
  for (int j = 0; j < 8; ++j) A.a[j] = 0.f;
  uint4 sv = *reinterpret_cast<const uint4*>(xw + (size_t)perm[r] * DIM + c * 8);
  fma8(A, sv, di * di);  // self loop (permuted)
  agg_loop2(xw, colidx2, colnorm, row_start[r], row_start[r + 1], c, A);
  epilogue8(A, bias, slope[0], c);
  float4 w0 = *reinterpret_cast<const float4*>(&wsum[c * 8]);
  float4 w1 = *reinterpret_cast<const float4*>(&wsum[c * 8 + 4]);
  float d = A.a[0] * w0.x + A.a[1] * w0.y + A.a[2] * w0.z + A.a[3] * w0.w +
            A.a[4] * w1.x + A.a[5] * w1.y + A.a[6] * w1.z + A.a[7] * w1.w;
#pragma unroll
  for (int off = 16; off > 0; off >>= 1) d += __shfl_down(d, off, 32);
  if (c == 0) neg[r] = d;
}

// ---------------- column sums (2-stage, no atomics) ----------------

__global__ __launch_bounds__(256) void k_colsum(const ushort* __restrict__ z1,
                                                float* __restrict__ partial) {
  __shared__ float red[8 * 256];
  const int t = threadIdx.x;
  const int c8 = t & 31;       // col block of 8
  const int g = t >> 5;        // row group 0..7
  float s[8] = {0.f, 0.f, 0.f, 0.f, 0.f, 0.f, 0.f, 0.f};
  for (int r = blockIdx.x * 8 + g; r < N_NODES; r += 8 * CSB) {
    uint4 v = *reinterpret_cast<const uint4*>(z1 + (size_t)r * DIM + c8 * 8);
    s[0] += bf_lo(v.x); s[1] += bf_hi(v.x);
    s[2] += bf_lo(v.y); s[3] += bf_hi(v.y);
    s[4] += bf_lo(v.z); s[5] += bf_hi(v.z);
    s[6] += bf_lo(v.w); s[7] += bf_hi(v.w);
  }
#pragma unroll
  for (int j = 0; j < 8; ++j) red[g * 256 + c8 * 8 + j] = s[j];
  __syncthreads();
  // thread t owns column t: sum the 8 row-groups (conflict-free reads)
  float tot = 0.f;
#pragma unroll
  for (int g2 = 0; g2 < 8; ++g2) tot += red[g2 * 256 + t];
  partial[blockIdx.x * 256 + t] = tot;  // coalesced
}

// reduce partials + sigmoid + wsum = disc_W @ summary, one block
__global__ __launch_bounds__(256) void k_wsum(const float* __restrict__ partial,
                                              const float* __restrict__ disc_W,
                                              float* __restrict__ wsum) {
  __shared__ float s[DIM];
  const int t = threadIdx.x;
  float a0 = 0.f, a1 = 0.f, a2 = 0.f, a3 = 0.f;
  for (int b = 0; b < CSB; b += 4) {
    a0 += partial[(b + 0) * 256 + t];
    a1 += partial[(b + 1) * 256 + t];
    a2 += partial[(b + 2) * 256 + t];
    a3 += partial[(b + 3) * 256 + t];
  }
  float m = (a0 + a1 + a2 + a3) * (1.0f / (float)N_NODES);
  s[t] = 1.0f / (1.0f + expf(-m));
  __syncthreads();
  float acc = 0.f;
  for (int j = 0; j < DIM; j += 4) {
    float4 w4 = *reinterpret_cast<const float4*>(&disc_W[t * DIM + j]);
    acc += w4.x * s[j] + w4.y * s[j + 1] + w4.z * s[j + 2] + w4.w * s[j + 3];
  }
  wsum[t] = acc;
}

__global__ __launch_bounds__(256) void k_pos(const ushort* __restrict__ z1,
                                             const float* __restrict__ wsum,
                                             float* __restrict__ pos) {
  const int wid = (blockIdx.x * blockDim.x + threadIdx.x) >> 6;
  const int lane = threadIdx.x & 63;
  if (wid >= N_NODES) return;
  uint2 v = *reinterpret_cast<const uint2*>(z1 + (size_t)wid * DIM + lane * 4);
  float4 w4 = *reinterpret_cast<const float4*>(&wsum[lane * 4]);
  float d = bf_lo(v.x) * w4.x + bf_hi(v.x) * w4.y + bf_lo(v.y) * w4.z + bf_hi(v.y) * w4.w;
#pragma unroll
  for (int off = 32; off > 0; off >>= 1) d += __shfl_down(d, off);
  if (lane == 0) pos[wid] = d;
}

// ---------------- launch ----------------

extern "C" void kernel_launch(void* const* d_in, const int* in_sizes, int n_in,
                              void* d_out, int out_size, void* d_ws, size_t ws_size,
                              hipStream_t stream) {
  const float* x      = (const float*)d_in[0];
  const float* W      = (const float*)d_in[1];
  const float* b      = (const float*)d_in[2];
  const float* a      = (const float*)d_in[3];
  const float* disc_W = (const float*)d_in[4];
  const int*   eidx   = (const int*)d_in[5];
  const int*   perm   = (const int*)d_in[6];
  const int* src = eidx;
  const int* dst = eidx + N_EDGES;

  constexpr size_t SZ_BFM  = (size_t)N_NODES * DIM * 2;  // 25.6 MB
  constexpr size_t OFF_XW  = 0;
  constexpr size_t OFF_Z1  = OFF_XW + SZ_BFM;
  constexpr size_t OFF_WT  = OFF_Z1 + SZ_BFM;
  constexpr size_t OFF_DEG = OFF_WT + 131072;
  constexpr size_t OFF_DNV = OFF_DEG + 200192;
  constexpr size_t OFF_RS  = OFF_DNV + 200192;
  constexpr size_t OFF_CUR = OFF_RS + 200448;
  constexpr size_t OFF_CI  = OFF_CUR + 200192;
  constexpr size_t OFF_CI2 = OFF_CI + (size_t)N_EDGES * 4;
  constexpr size_t OFF_CN  = OFF_CI2 + (size_t)N_EDGES * 4;
  constexpr size_t OFF_WSM = OFF_CN + (size_t)N_EDGES * 4;
  constexpr size_t OFF_BS  = OFF_WSM + 1024;
  constexpr size_t OFF_BO  = OFF_BS + 1024;
  constexpr size_t OFF_PT  = OFF_BO + 1024;
  constexpr size_t NEED    = OFF_PT + (size_t)CSB * 256 * 4;
  if (ws_size < NEED) return;

  char* ws = (char*)d_ws;
  ushort* xw     = (ushort*)(ws + OFF_XW);
  ushort* z1     = (ushort*)(ws + OFF_Z1);
  ushort* Wt     = (ushort*)(ws + OFF_WT);
  int*    deg    = (int*)(ws + OFF_DEG);
  float*  dinv   = (float*)(ws + OFF_DNV);
  int*    rowst  = (int*)(ws + OFF_RS);
  int*    cursor = (int*)(ws + OFF_CUR);
  int*    colidx = (int*)(ws + OFF_CI);
  int*    colidx2= (int*)(ws + OFF_CI2);
  float*  colnorm= (float*)(ws + OFF_CN);
  float*  wsum   = (float*)(ws + OFF_WSM);
  int*    bsum   = (int*)(ws + OFF_BS);
  int*    boff   = (int*)(ws + OFF_BO);
  float*  partial= (float*)(ws + OFF_PT);

  float* pos = (float*)d_out;
  float* neg = pos + N_NODES;

  hipMemsetAsync(deg, 0, N_NODES * sizeof(int), stream);

  k_deg<<<(N_EDGES + 255) / 256, 256, 0, stream>>>(dst, deg);
  k_bsum<<<NB, 256, 0, stream>>>(deg, dinv, bsum);
  k_bscan<<<1, 256, 0, stream>>>(bsum, boff, rowst);
  k_rowstart<<<NB, 256, 0, stream>>>(deg, boff, rowst, cursor);
  k_scatter<<<(N_EDGES + 255) / 256, 256, 0, stream>>>(src, dst, perm, dinv,
                                                       cursor, colidx, colidx2, colnorm);

  k_prep<<<DIM, DIM, 0, stream>>>(W, Wt);
  k_gemm<<<(N_NODES + 127) / 128, 512, 0, stream>>>(x, Wt, xw);

  // 2 rows per wave -> 25000 waves -> 6250 blocks
  k_agg1<<<(N_NODES / 2 * 64) / 256, 256, 0, stream>>>(
      xw, rowst, colidx, colnorm, dinv, b, a, z1);
  k_colsum<<<CSB, 256, 0, stream>>>(z1, partial);
  k_wsum<<<1, 256, 0, stream>>>(partial, disc_W, wsum);

  k_pos<<<(N_NODES * 64 + 255) / 256, 256, 0, stream>>>(z1, wsum, pos);
  k_agg2_neg<<<(N_NODES / 2 * 64) / 256, 256, 0, stream>>>(
      xw, rowst, colidx2, colnorm, perm, dinv, b, a, wsum, neg);
}